// Round 1
// baseline (853.800 us; speedup 1.0000x reference)
//
#include <hip/hip_runtime.h>
#include <hip/hip_bf16.h>

// Problem constants
#define T_DIM 64
#define B_DIM 512
#define D_DIM 1536
#define H_DIM 1024
#define M_DIM (T_DIM * B_DIM)   // 32768 rows through the MLP
#define DISCOUNT 0.997f
#define LAM 0.95f

// GEMM tiling
#define BM 128
#define BN 128
#define BK 64

typedef __bf16 bf16x8 __attribute__((ext_vector_type(8)));
typedef float  f32x4  __attribute__((ext_vector_type(4)));

__device__ __forceinline__ void async_load16(const void* g, void* l) {
    __builtin_amdgcn_global_load_lds(
        (const __attribute__((address_space(1))) void*)g,
        (__attribute__((address_space(3))) void*)l,
        16, 0, 0);
}

__device__ __forceinline__ unsigned short f2bf_raw(float f) {
    __hip_bfloat16 h = __float2bfloat16(f);
    return *reinterpret_cast<unsigned short*>(&h);
}

// ---------------------------------------------------------------------------
// feat fp32 -> bf16, vectorized (float4 in, ushort4 out)
// ---------------------------------------------------------------------------
__global__ __launch_bounds__(256) void cvt_bf16_kernel(
    const float* __restrict__ x, __hip_bfloat16* __restrict__ y, long n4) {
    long i = (long)blockIdx.x * blockDim.x + threadIdx.x;
    if (i >= n4) return;
    float4 v = reinterpret_cast<const float4*>(x)[i];
    ushort4 o;
    o.x = f2bf_raw(v.x);
    o.y = f2bf_raw(v.y);
    o.z = f2bf_raw(v.z);
    o.w = f2bf_raw(v.w);
    reinterpret_cast<ushort4*>(y)[i] = o;
}

// ---------------------------------------------------------------------------
// W (K x N, fp32 row-major) -> Wt (N x K, bf16 row-major)  [transpose+convert]
// ---------------------------------------------------------------------------
__global__ __launch_bounds__(256) void transpose_cvt_kernel(
    const float* __restrict__ W, __hip_bfloat16* __restrict__ Wt, int K, int N) {
    __shared__ float tile[32][33];
    int k0 = blockIdx.x * 32, n0 = blockIdx.y * 32;
    int tx = threadIdx.x, ty = threadIdx.y;  // 32 x 8
    #pragma unroll
    for (int r = ty; r < 32; r += 8)
        tile[r][tx] = W[(size_t)(k0 + r) * N + n0 + tx];
    __syncthreads();
    #pragma unroll
    for (int r = ty; r < 32; r += 8)
        Wt[(size_t)(n0 + r) * K + k0 + tx] = __float2bfloat16(tile[tx][r]);
}

// ---------------------------------------------------------------------------
// C[m][n] = silu( sum_k A[m][k] * Bt[n][k] + bias[n] ), output bf16
// A: M x K bf16 row-major; Bt: N x K bf16 row-major (transposed weights)
// 128x128 tile / block, 4 waves in 2x2, each wave 64x64 = 4x4 MFMA tiles
// ---------------------------------------------------------------------------
__global__ __launch_bounds__(256) void gemm_silu_kernel(
    const __hip_bfloat16* __restrict__ A,
    const __hip_bfloat16* __restrict__ Bt,
    const float* __restrict__ bias,
    __hip_bfloat16* __restrict__ C,
    int M, int N, int K) {

    __shared__ alignas(16) __hip_bfloat16 As[BM * BK];  // 16 KB
    __shared__ alignas(16) __hip_bfloat16 Bs[BN * BK];  // 16 KB

    const int tid  = threadIdx.x;
    const int wave = tid >> 6;
    const int lane = tid & 63;
    const int sub  = lane >> 3;        // row within 8-row staging chunk
    const int colv = (lane & 7) * 8;   // bf16 col offset within staging row
    const int quad = lane >> 4;        // 0..3
    const int r16  = lane & 15;        // 0..15
    const int wm   = wave & 1;         // wave row in 2x2
    const int wn   = wave >> 1;        // wave col in 2x2

    const int m0 = blockIdx.y * BM;
    const int n0 = blockIdx.x * BN;

    f32x4 acc[4][4];
    #pragma unroll
    for (int i = 0; i < 4; ++i)
        #pragma unroll
        for (int j = 0; j < 4; ++j)
            acc[i][j] = (f32x4){0.f, 0.f, 0.f, 0.f};

    for (int k0 = 0; k0 < K; k0 += BK) {
        // stage A tile (128 x 64) and B tile (128 x 64): 4 async 1KB wave-loads each
        #pragma unroll
        for (int i = 0; i < 4; ++i) {
            int chunk = wave * 4 + i;  // 0..15, 8 rows per chunk
            const __hip_bfloat16* ga =
                A + (size_t)(m0 + chunk * 8 + sub) * K + k0 + colv;
            async_load16(ga, &As[chunk * 512]);
        }
        #pragma unroll
        for (int i = 0; i < 4; ++i) {
            int chunk = wave * 4 + i;
            const __hip_bfloat16* gb =
                Bt + (size_t)(n0 + chunk * 8 + sub) * K + k0 + colv;
            async_load16(gb, &Bs[chunk * 512]);
        }
        __syncthreads();

        #pragma unroll
        for (int kk = 0; kk < BK; kk += 32) {
            bf16x8 af[4], bf[4];
            #pragma unroll
            for (int i = 0; i < 4; ++i) {
                int m_l = wm * 64 + i * 16 + r16;
                af[i] = *reinterpret_cast<const bf16x8*>(&As[m_l * BK + kk + quad * 8]);
                int n_l = wn * 64 + i * 16 + r16;
                bf[i] = *reinterpret_cast<const bf16x8*>(&Bs[n_l * BK + kk + quad * 8]);
            }
            #pragma unroll
            for (int i = 0; i < 4; ++i)
                #pragma unroll
                for (int j = 0; j < 4; ++j)
                    acc[i][j] = __builtin_amdgcn_mfma_f32_16x16x32_bf16(
                        af[i], bf[j], acc[i][j], 0, 0, 0);
        }
        __syncthreads();
    }

    // epilogue: bias + SiLU + bf16 store
    // C/D layout: col = lane&15, row = quad*4 + reg   [verified m89]
    #pragma unroll
    for (int j = 0; j < 4; ++j) {
        int col = n0 + wn * 64 + j * 16 + r16;
        float bj = bias[col];
        #pragma unroll
        for (int i = 0; i < 4; ++i) {
            int row_base = m0 + wm * 64 + i * 16 + quad * 4;
            #pragma unroll
            for (int rr = 0; rr < 4; ++rr) {
                float v = acc[i][j][rr] + bj;
                float s = v / (1.f + __expf(-v));
                C[(size_t)(row_base + rr) * N + col] = __float2bfloat16(s);
            }
        }
    }
}

// ---------------------------------------------------------------------------
// value[m] = sum_n H[m][n] * Wo[n] + bo      (N = 1024 fixed; 1 wave / row)
// ---------------------------------------------------------------------------
__global__ __launch_bounds__(256) void gemv_value_kernel(
    const __hip_bfloat16* __restrict__ H,
    const float* __restrict__ Wo,
    const float* __restrict__ bo_p,
    float* __restrict__ value, int M) {
    int wave = threadIdx.x >> 6, lane = threadIdx.x & 63;
    int row = blockIdx.x * 4 + wave;
    if (row >= M) return;
    const __hip_bfloat16* hrow = H + (size_t)row * H_DIM;
    float sum = 0.f;
    #pragma unroll
    for (int half = 0; half < 2; ++half) {
        int col = half * 512 + lane * 8;
        uint4 raw = *reinterpret_cast<const uint4*>(hrow + col);
        const __hip_bfloat16* hp = reinterpret_cast<const __hip_bfloat16*>(&raw);
        #pragma unroll
        for (int e = 0; e < 8; ++e)
            sum += __bfloat162float(hp[e]) * Wo[col + e];
    }
    #pragma unroll
    for (int off = 32; off > 0; off >>= 1)
        sum += __shfl_down(sum, off, 64);
    if (lane == 0) value[row] = sum + bo_p[0];
}

// ---------------------------------------------------------------------------
// GAE backward scan. value: (T,B) fp32. out: ret (63x512) then baseline.
// ---------------------------------------------------------------------------
__global__ __launch_bounds__(256) void gae_kernel(
    const float* __restrict__ value,
    const float* __restrict__ reward,
    const float* __restrict__ cont,
    float* __restrict__ out) {
    int b = blockIdx.x * blockDim.x + threadIdx.x;
    if (b >= B_DIM) return;
    float adv = 0.f;
    float v_next = value[(T_DIM - 1) * B_DIM + b];
    for (int t = T_DIM - 2; t >= 0; --t) {
        float v_t  = value[t * B_DIM + b];
        float disc = cont[(t + 1) * B_DIM + b] * DISCOUNT;
        float delta = reward[t * B_DIM + b] + disc * v_next - v_t;
        adv = delta + disc * LAM * adv;
        out[t * B_DIM + b] = adv + v_t;                           // ret
        out[(T_DIM - 1) * B_DIM + t * B_DIM + b] = v_t;           // baseline
        v_next = v_t;
    }
}

// ---------------------------------------------------------------------------
extern "C" void kernel_launch(void* const* d_in, const int* in_sizes, int n_in,
                              void* d_out, int out_size, void* d_ws, size_t ws_size,
                              hipStream_t stream) {
    const float* feat   = (const float*)d_in[0];
    const float* reward = (const float*)d_in[1];
    const float* cont   = (const float*)d_in[2];
    const float* W[4]   = {(const float*)d_in[3], (const float*)d_in[5],
                           (const float*)d_in[7], (const float*)d_in[9]};
    const float* bias[4] = {(const float*)d_in[4], (const float*)d_in[6],
                            (const float*)d_in[8], (const float*)d_in[10]};
    const float* Wo = (const float*)d_in[11];
    const float* bo = (const float*)d_in[12];
    float* out = (float*)d_out;

    // workspace layout
    char* ws = (char*)d_ws;
    __hip_bfloat16* Xb = (__hip_bfloat16*)ws; ws += (size_t)M_DIM * D_DIM * 2;   // 96 MB
    __hip_bfloat16* Ha = (__hip_bfloat16*)ws; ws += (size_t)M_DIM * H_DIM * 2;   // 64 MB
    __hip_bfloat16* Hb = (__hip_bfloat16*)ws; ws += (size_t)M_DIM * H_DIM * 2;   // 64 MB
    __hip_bfloat16* Wt0 = (__hip_bfloat16*)ws; ws += (size_t)H_DIM * D_DIM * 2;  // 3 MB
    __hip_bfloat16* Wt1 = (__hip_bfloat16*)ws; ws += (size_t)H_DIM * H_DIM * 2;
    __hip_bfloat16* Wt2 = (__hip_bfloat16*)ws; ws += (size_t)H_DIM * H_DIM * 2;
    __hip_bfloat16* Wt3 = (__hip_bfloat16*)ws; ws += (size_t)H_DIM * H_DIM * 2;
    float* value = (float*)ws; ws += (size_t)M_DIM * 4;

    // 1. feat -> bf16
    long n4 = (long)M_DIM * D_DIM / 4;
    cvt_bf16_kernel<<<(int)((n4 + 255) / 256), 256, 0, stream>>>(feat, Xb, n4);

    // 2. weights -> transposed bf16
    transpose_cvt_kernel<<<dim3(D_DIM / 32, H_DIM / 32), dim3(32, 8), 0, stream>>>(
        W[0], Wt0, D_DIM, H_DIM);
    transpose_cvt_kernel<<<dim3(H_DIM / 32, H_DIM / 32), dim3(32, 8), 0, stream>>>(
        W[1], Wt1, H_DIM, H_DIM);
    transpose_cvt_kernel<<<dim3(H_DIM / 32, H_DIM / 32), dim3(32, 8), 0, stream>>>(
        W[2], Wt2, H_DIM, H_DIM);
    transpose_cvt_kernel<<<dim3(H_DIM / 32, H_DIM / 32), dim3(32, 8), 0, stream>>>(
        W[3], Wt3, H_DIM, H_DIM);

    // 3. MLP: 4 GEMM + SiLU layers
    dim3 g0(H_DIM / BN, M_DIM / BM);  // (8, 256)
    gemm_silu_kernel<<<g0, 256, 0, stream>>>(Xb, Wt0, bias[0], Ha, M_DIM, H_DIM, D_DIM);
    gemm_silu_kernel<<<g0, 256, 0, stream>>>(Ha, Wt1, bias[1], Hb, M_DIM, H_DIM, H_DIM);
    gemm_silu_kernel<<<g0, 256, 0, stream>>>(Hb, Wt2, bias[2], Ha, M_DIM, H_DIM, H_DIM);
    gemm_silu_kernel<<<g0, 256, 0, stream>>>(Ha, Wt3, bias[3], Hb, M_DIM, H_DIM, H_DIM);

    // 4. value head GEMV
    gemv_value_kernel<<<M_DIM / 4, 256, 0, stream>>>(Hb, Wo, bo, value, M_DIM);

    // 5. GAE scan
    gae_kernel<<<2, 256, 0, stream>>>(value, reward, cont, out);
}

// Round 2
// 790.594 us; speedup vs baseline: 1.0799x; 1.0799x over previous
//
#include <hip/hip_runtime.h>
#include <hip/hip_bf16.h>

// Problem constants
#define T_DIM 64
#define B_DIM 512
#define D_DIM 1536
#define H_DIM 1024
#define M_DIM (T_DIM * B_DIM)   // 32768 rows through the MLP
#define DISCOUNT 0.997f
#define LAM 0.95f

// GEMM tiling (fixed shape: M=32768, N=1024 -> tile grid 256 x 8)
#define BM 128
#define BN 128
#define BK 64
#define TILES_M 256
#define TILES_N 8
#define N_XCD 8

typedef __bf16 bf16x8 __attribute__((ext_vector_type(8)));
typedef float  f32x4  __attribute__((ext_vector_type(4)));

__device__ __forceinline__ void async_load16(const void* g, void* l) {
    __builtin_amdgcn_global_load_lds(
        (const __attribute__((address_space(1))) void*)g,
        (__attribute__((address_space(3))) void*)l,
        16, 0, 0);
}

__device__ __forceinline__ unsigned short f2bf_raw(float f) {
    __hip_bfloat16 h = __float2bfloat16(f);
    return *reinterpret_cast<unsigned short*>(&h);
}

// ---------------------------------------------------------------------------
// feat fp32 -> bf16, vectorized (float4 in, ushort4 out)
// ---------------------------------------------------------------------------
__global__ __launch_bounds__(256) void cvt_bf16_kernel(
    const float* __restrict__ x, __hip_bfloat16* __restrict__ y, long n4) {
    long i = (long)blockIdx.x * blockDim.x + threadIdx.x;
    if (i >= n4) return;
    float4 v = reinterpret_cast<const float4*>(x)[i];
    ushort4 o;
    o.x = f2bf_raw(v.x);
    o.y = f2bf_raw(v.y);
    o.z = f2bf_raw(v.z);
    o.w = f2bf_raw(v.w);
    reinterpret_cast<ushort4*>(y)[i] = o;
}

// ---------------------------------------------------------------------------
// All 4 weight transposes in one launch. W (K x N fp32) -> Wt (N x K bf16).
// Grid (48, 32, 4); z selects the layer; z>0 layers have K=1024 (x<32).
// ---------------------------------------------------------------------------
__global__ __launch_bounds__(256) void transpose_cvt_all_kernel(
    const float* __restrict__ W0, const float* __restrict__ W1,
    const float* __restrict__ W2, const float* __restrict__ W3,
    __hip_bfloat16* __restrict__ T0, __hip_bfloat16* __restrict__ T1,
    __hip_bfloat16* __restrict__ T2, __hip_bfloat16* __restrict__ T3) {
    __shared__ float tile[32][33];
    int z = blockIdx.z;
    const float* W;
    __hip_bfloat16* Tt;
    int K;
    if (z == 0)      { W = W0; Tt = T0; K = D_DIM; }
    else if (z == 1) { W = W1; Tt = T1; K = H_DIM; }
    else if (z == 2) { W = W2; Tt = T2; K = H_DIM; }
    else             { W = W3; Tt = T3; K = H_DIM; }
    int k0 = blockIdx.x * 32, n0 = blockIdx.y * 32;
    if (k0 >= K) return;
    int tx = threadIdx.x, ty = threadIdx.y;  // 32 x 8
    #pragma unroll
    for (int r = ty; r < 32; r += 8)
        tile[r][tx] = W[(size_t)(k0 + r) * H_DIM + n0 + tx];
    __syncthreads();
    #pragma unroll
    for (int r = ty; r < 32; r += 8)
        Tt[(size_t)(n0 + r) * K + k0 + tx] = __float2bfloat16(tile[tx][r]);
}

// ---------------------------------------------------------------------------
// C[m][n] = silu( sum_k A[m][k] * Bt[n][k] + bias[n] ), output bf16
// A: M x K bf16 row-major; Bt: N x K bf16 row-major (transposed weights)
// 128x128 tile / block, 4 waves in 2x2, each wave 64x64 = 4x4 MFMA tiles.
//
// XCD swizzle: hw block l -> xcd = l%8, each xcd owns rows [xcd*32, +32),
// local id walks the 8 N-tiles fastest so one A panel is consumed by 8
// temporally-adjacent blocks on the same XCD; Wt stays L2-resident.
//
// LDS XOR swizzle: logical 16B slot c of row r stored at physical slot
// c ^ (r & 7). global_load_lds dest is base+lane*16 (fixed), so the swizzle
// is applied by permuting each lane's *global* source column. Readers
// un-swizzle; quad lanes 0..7 then cover all 32 banks (2-way alias = free).
// ---------------------------------------------------------------------------
__global__ __launch_bounds__(256) void gemm_silu_kernel(
    const __hip_bfloat16* __restrict__ A,
    const __hip_bfloat16* __restrict__ Bt,
    const float* __restrict__ bias,
    __hip_bfloat16* __restrict__ C,
    int K) {

    __shared__ alignas(16) __hip_bfloat16 As[BM * BK];  // 16 KB
    __shared__ alignas(16) __hip_bfloat16 Bs[BN * BK];  // 16 KB

    const int tid  = threadIdx.x;
    const int wave = tid >> 6;
    const int lane = tid & 63;
    const int sub  = lane >> 3;        // staging row within 8-row chunk
    const int quad = lane >> 4;        // 0..3
    const int r16  = lane & 15;        // 0..15
    const int wm   = wave & 1;         // wave row in 2x2
    const int wn   = wave >> 1;        // wave col in 2x2

    // XCD-aware tile assignment
    const int l     = blockIdx.x;
    const int xcd   = l & (N_XCD - 1);
    const int local = l >> 3;
    const int tn    = local & (TILES_N - 1);
    const int tm    = (xcd << 5) | (local >> 3);
    const int m0 = tm * BM;
    const int n0 = tn * BN;

    // swizzled global column for this lane's staging load
    const int scol = (((lane & 7) ^ sub) << 3);

    f32x4 acc[4][4];
    #pragma unroll
    for (int i = 0; i < 4; ++i)
        #pragma unroll
        for (int j = 0; j < 4; ++j)
            acc[i][j] = (f32x4){0.f, 0.f, 0.f, 0.f};

    for (int k0 = 0; k0 < K; k0 += BK) {
        #pragma unroll
        for (int i = 0; i < 4; ++i) {
            int chunk = wave * 4 + i;  // 0..15, 8 rows per chunk
            const __hip_bfloat16* ga =
                A + (size_t)(m0 + chunk * 8 + sub) * K + k0 + scol;
            async_load16(ga, &As[chunk * 512]);
        }
        #pragma unroll
        for (int i = 0; i < 4; ++i) {
            int chunk = wave * 4 + i;
            const __hip_bfloat16* gb =
                Bt + (size_t)(n0 + chunk * 8 + sub) * K + k0 + scol;
            async_load16(gb, &Bs[chunk * 512]);
        }
        __syncthreads();

        #pragma unroll
        for (int kk = 0; kk < BK; kk += 32) {
            bf16x8 af[4], bf[4];
            #pragma unroll
            for (int i = 0; i < 4; ++i) {
                int m_l = wm * 64 + i * 16 + r16;
                int sa  = ((kk >> 3) + quad) ^ (m_l & 7);
                af[i] = *reinterpret_cast<const bf16x8*>(&As[m_l * BK + sa * 8]);
                int n_l = wn * 64 + i * 16 + r16;
                int sb  = ((kk >> 3) + quad) ^ (n_l & 7);
                bf[i] = *reinterpret_cast<const bf16x8*>(&Bs[n_l * BK + sb * 8]);
            }
            #pragma unroll
            for (int i = 0; i < 4; ++i)
                #pragma unroll
                for (int j = 0; j < 4; ++j)
                    acc[i][j] = __builtin_amdgcn_mfma_f32_16x16x32_bf16(
                        af[i], bf[j], acc[i][j], 0, 0, 0);
        }
        __syncthreads();
    }

    // epilogue: bias + SiLU + bf16 store
    // C/D layout: col = lane&15, row = quad*4 + reg   [verified m89]
    #pragma unroll
    for (int j = 0; j < 4; ++j) {
        int col = n0 + wn * 64 + j * 16 + r16;
        float bj = bias[col];
        #pragma unroll
        for (int i = 0; i < 4; ++i) {
            int row_base = m0 + wm * 64 + i * 16 + quad * 4;
            #pragma unroll
            for (int rr = 0; rr < 4; ++rr) {
                float v = acc[i][j][rr] + bj;
                float s = v / (1.f + __expf(-v));
                C[(size_t)(row_base + rr) * H_DIM + col] = __float2bfloat16(s);
            }
        }
    }
}

// ---------------------------------------------------------------------------
// value[m] = sum_n H[m][n] * Wo[n] + bo      (N = 1024 fixed; 1 wave / row)
// ---------------------------------------------------------------------------
__global__ __launch_bounds__(256) void gemv_value_kernel(
    const __hip_bfloat16* __restrict__ H,
    const float* __restrict__ Wo,
    const float* __restrict__ bo_p,
    float* __restrict__ value, int M) {
    int wave = threadIdx.x >> 6, lane = threadIdx.x & 63;
    int row = blockIdx.x * 4 + wave;
    if (row >= M) return;
    const __hip_bfloat16* hrow = H + (size_t)row * H_DIM;
    float sum = 0.f;
    #pragma unroll
    for (int half = 0; half < 2; ++half) {
        int col = half * 512 + lane * 8;
        uint4 raw = *reinterpret_cast<const uint4*>(hrow + col);
        const __hip_bfloat16* hp = reinterpret_cast<const __hip_bfloat16*>(&raw);
        #pragma unroll
        for (int e = 0; e < 8; ++e)
            sum += __bfloat162float(hp[e]) * Wo[col + e];
    }
    #pragma unroll
    for (int off = 32; off > 0; off >>= 1)
        sum += __shfl_down(sum, off, 64);
    if (lane == 0) value[row] = sum + bo_p[0];
}

// ---------------------------------------------------------------------------
// GAE backward scan. value: (T,B) fp32. out: ret (63x512) then baseline.
// 8 blocks x 64 threads: one thread per batch column, spread across CUs.
// ---------------------------------------------------------------------------
__global__ __launch_bounds__(64) void gae_kernel(
    const float* __restrict__ value,
    const float* __restrict__ reward,
    const float* __restrict__ cont,
    float* __restrict__ out) {
    int b = blockIdx.x * blockDim.x + threadIdx.x;
    if (b >= B_DIM) return;
    float adv = 0.f;
    float v_next = value[(T_DIM - 1) * B_DIM + b];
    for (int t = T_DIM - 2; t >= 0; --t) {
        float v_t  = value[t * B_DIM + b];
        float disc = cont[(t + 1) * B_DIM + b] * DISCOUNT;
        float delta = reward[t * B_DIM + b] + disc * v_next - v_t;
        adv = delta + disc * LAM * adv;
        out[t * B_DIM + b] = adv + v_t;                           // ret
        out[(T_DIM - 1) * B_DIM + t * B_DIM + b] = v_t;           // baseline
        v_next = v_t;
    }
}

// ---------------------------------------------------------------------------
extern "C" void kernel_launch(void* const* d_in, const int* in_sizes, int n_in,
                              void* d_out, int out_size, void* d_ws, size_t ws_size,
                              hipStream_t stream) {
    const float* feat   = (const float*)d_in[0];
    const float* reward = (const float*)d_in[1];
    const float* cont   = (const float*)d_in[2];
    const float* W[4]   = {(const float*)d_in[3], (const float*)d_in[5],
                           (const float*)d_in[7], (const float*)d_in[9]};
    const float* bias[4] = {(const float*)d_in[4], (const float*)d_in[6],
                            (const float*)d_in[8], (const float*)d_in[10]};
    const float* Wo = (const float*)d_in[11];
    const float* bo = (const float*)d_in[12];
    float* out = (float*)d_out;

    // workspace layout
    char* ws = (char*)d_ws;
    __hip_bfloat16* Xb = (__hip_bfloat16*)ws; ws += (size_t)M_DIM * D_DIM * 2;   // 96 MB
    __hip_bfloat16* Ha = (__hip_bfloat16*)ws; ws += (size_t)M_DIM * H_DIM * 2;   // 64 MB
    __hip_bfloat16* Hb = (__hip_bfloat16*)ws; ws += (size_t)M_DIM * H_DIM * 2;   // 64 MB
    __hip_bfloat16* Wt0 = (__hip_bfloat16*)ws; ws += (size_t)H_DIM * D_DIM * 2;  // 3 MB
    __hip_bfloat16* Wt1 = (__hip_bfloat16*)ws; ws += (size_t)H_DIM * H_DIM * 2;
    __hip_bfloat16* Wt2 = (__hip_bfloat16*)ws; ws += (size_t)H_DIM * H_DIM * 2;
    __hip_bfloat16* Wt3 = (__hip_bfloat16*)ws; ws += (size_t)H_DIM * H_DIM * 2;
    float* value = (float*)ws; ws += (size_t)M_DIM * 4;

    // 1. feat -> bf16
    long n4 = (long)M_DIM * D_DIM / 4;
    cvt_bf16_kernel<<<(int)((n4 + 255) / 256), 256, 0, stream>>>(feat, Xb, n4);

    // 2. all weight transposes, one launch
    transpose_cvt_all_kernel<<<dim3(D_DIM / 32, H_DIM / 32, 4), dim3(32, 8), 0, stream>>>(
        W[0], W[1], W[2], W[3], Wt0, Wt1, Wt2, Wt3);

    // 3. MLP: 4 GEMM + SiLU layers (1D grid, XCD-swizzled inside)
    const int nblocks = TILES_M * TILES_N;  // 2048
    gemm_silu_kernel<<<nblocks, 256, 0, stream>>>(Xb, Wt0, bias[0], Ha, D_DIM);
    gemm_silu_kernel<<<nblocks, 256, 0, stream>>>(Ha, Wt1, bias[1], Hb, H_DIM);
    gemm_silu_kernel<<<nblocks, 256, 0, stream>>>(Hb, Wt2, bias[2], Ha, H_DIM);
    gemm_silu_kernel<<<nblocks, 256, 0, stream>>>(Ha, Wt3, bias[3], Hb, H_DIM);

    // 4. value head GEMV
    gemv_value_kernel<<<M_DIM / 4, 256, 0, stream>>>(Hb, Wo, bo, value, M_DIM);

    // 5. GAE scan
    gae_kernel<<<8, 64, 0, stream>>>(value, reward, cont, out);
}

// Round 3
// 758.342 us; speedup vs baseline: 1.1259x; 1.0425x over previous
//
#include <hip/hip_runtime.h>
#include <hip/hip_bf16.h>

// Problem constants
#define T_DIM 64
#define B_DIM 512
#define D_DIM 1536
#define H_DIM 1024
#define M_DIM (T_DIM * B_DIM)   // 32768 rows through the MLP
#define DISCOUNT 0.997f
#define LAM 0.95f

// GEMM tiling (fixed shape: M=32768, N=1024 -> tile grid 256 x 8)
#define BM 128
#define BN 128
#define BK 64
#define TILES_M 256
#define TILES_N 8
#define N_XCD 8

typedef __bf16 bf16x8 __attribute__((ext_vector_type(8)));
typedef float  f32x4  __attribute__((ext_vector_type(4)));

__device__ __forceinline__ void async_load16(const void* g, void* l) {
    __builtin_amdgcn_global_load_lds(
        (const __attribute__((address_space(1))) void*)g,
        (__attribute__((address_space(3))) void*)l,
        16, 0, 0);
}

__device__ __forceinline__ unsigned short f2bf_raw(float f) {
    __hip_bfloat16 h = __float2bfloat16(f);
    return *reinterpret_cast<unsigned short*>(&h);
}

// ---------------------------------------------------------------------------
// feat fp32 -> bf16, vectorized (float4 in, ushort4 out)
// ---------------------------------------------------------------------------
__global__ __launch_bounds__(256) void cvt_bf16_kernel(
    const float* __restrict__ x, __hip_bfloat16* __restrict__ y, long n4) {
    long i = (long)blockIdx.x * blockDim.x + threadIdx.x;
    if (i >= n4) return;
    float4 v = reinterpret_cast<const float4*>(x)[i];
    ushort4 o;
    o.x = f2bf_raw(v.x);
    o.y = f2bf_raw(v.y);
    o.z = f2bf_raw(v.z);
    o.w = f2bf_raw(v.w);
    reinterpret_cast<ushort4*>(y)[i] = o;
}

// ---------------------------------------------------------------------------
// All 4 weight transposes in one launch. W (K x N fp32) -> Wt (N x K bf16).
// ---------------------------------------------------------------------------
__global__ __launch_bounds__(256) void transpose_cvt_all_kernel(
    const float* __restrict__ W0, const float* __restrict__ W1,
    const float* __restrict__ W2, const float* __restrict__ W3,
    __hip_bfloat16* __restrict__ T0, __hip_bfloat16* __restrict__ T1,
    __hip_bfloat16* __restrict__ T2, __hip_bfloat16* __restrict__ T3) {
    __shared__ float tile[32][33];
    int z = blockIdx.z;
    const float* W;
    __hip_bfloat16* Tt;
    int K;
    if (z == 0)      { W = W0; Tt = T0; K = D_DIM; }
    else if (z == 1) { W = W1; Tt = T1; K = H_DIM; }
    else if (z == 2) { W = W2; Tt = T2; K = H_DIM; }
    else             { W = W3; Tt = T3; K = H_DIM; }
    int k0 = blockIdx.x * 32, n0 = blockIdx.y * 32;
    if (k0 >= K) return;
    int tx = threadIdx.x, ty = threadIdx.y;  // 32 x 8
    #pragma unroll
    for (int r = ty; r < 32; r += 8)
        tile[r][tx] = W[(size_t)(k0 + r) * H_DIM + n0 + tx];
    __syncthreads();
    #pragma unroll
    for (int r = ty; r < 32; r += 8)
        Tt[(size_t)(n0 + r) * K + k0 + tx] = __float2bfloat16(tile[tx][r]);
}

// ---------------------------------------------------------------------------
// C[m][n] = silu( sum_k A[m][k] * Bt[n][k] + bias[n] ), output bf16.
// Software-pipelined K-loop: double-buffered LDS, raw s_barrier (asm), and
// per-iter vmcnt(0) that lands AFTER a full MFMA phase (loads for tile k are
// issued during compute of tile k-1, so the wait is near-free). One barrier
// per iteration; no compiler-inserted vmcnt(0)-before-issue drain.
//
// XCD swizzle: hw block l -> xcd = l%8; each xcd owns 32 consecutive M-tiles,
// N walked fastest -> A panel shared by 8 adjacent blocks, Wt L2-resident.
// LDS XOR swizzle (via permuted global source column): conflict-free reads.
// ---------------------------------------------------------------------------
__global__ __launch_bounds__(256) void gemm_silu_kernel(
    const __hip_bfloat16* __restrict__ A,
    const __hip_bfloat16* __restrict__ Bt,
    const float* __restrict__ bias,
    __hip_bfloat16* __restrict__ C,
    int K) {

    __shared__ alignas(16) __hip_bfloat16 As[2][BM * BK];  // 2 x 16 KB
    __shared__ alignas(16) __hip_bfloat16 Bs[2][BN * BK];  // 2 x 16 KB

    const int tid  = threadIdx.x;
    const int wave = tid >> 6;
    const int lane = tid & 63;
    const int sub  = lane >> 3;        // staging row within 8-row chunk
    const int quad = lane >> 4;        // 0..3
    const int r16  = lane & 15;        // 0..15
    const int wm   = wave & 1;         // wave row in 2x2
    const int wn   = wave >> 1;        // wave col in 2x2

    // XCD-aware tile assignment
    const int l     = blockIdx.x;
    const int xcd   = l & (N_XCD - 1);
    const int local = l >> 3;
    const int tn    = local & (TILES_N - 1);
    const int tm    = (xcd << 5) | (local >> 3);
    const int m0 = tm * BM;
    const int n0 = tn * BN;

    // swizzled global column for this lane's staging load
    const int scol = (((lane & 7) ^ sub) << 3);

    // hoisted staging row pointers (advance by BK per iteration)
    const __hip_bfloat16* ga[4];
    const __hip_bfloat16* gb[4];
    int ldsoff[4];
    #pragma unroll
    for (int i = 0; i < 4; ++i) {
        int chunk = wave * 4 + i;  // 0..15, 8 rows per chunk
        ga[i] = A  + (size_t)(m0 + chunk * 8 + sub) * K + scol;
        gb[i] = Bt + (size_t)(n0 + chunk * 8 + sub) * K + scol;
        ldsoff[i] = chunk * 512;
    }

    f32x4 acc[4][4];
    #pragma unroll
    for (int i = 0; i < 4; ++i)
        #pragma unroll
        for (int j = 0; j < 4; ++j)
            acc[i][j] = (f32x4){0.f, 0.f, 0.f, 0.f};

    const int niter = K / BK;

    // prologue: issue loads for tile 0 into buffer 0
    #pragma unroll
    for (int i = 0; i < 4; ++i) { async_load16(ga[i], &As[0][ldsoff[i]]); ga[i] += BK; }
    #pragma unroll
    for (int i = 0; i < 4; ++i) { async_load16(gb[i], &Bs[0][ldsoff[i]]); gb[i] += BK; }

    int p = 0;
    for (int k = 0; k < niter; ++k) {
        // tile-k loads were issued a full compute phase ago -> near-free wait
        asm volatile("s_waitcnt vmcnt(0)" ::: "memory");
        asm volatile("s_barrier" ::: "memory");

        // issue tile-(k+1) loads into the other buffer; they stay in flight
        // across this iteration's MFMA phase
        if (k + 1 < niter) {
            #pragma unroll
            for (int i = 0; i < 4; ++i) { async_load16(ga[i], &As[p ^ 1][ldsoff[i]]); ga[i] += BK; }
            #pragma unroll
            for (int i = 0; i < 4; ++i) { async_load16(gb[i], &Bs[p ^ 1][ldsoff[i]]); gb[i] += BK; }
        }

        #pragma unroll
        for (int kk = 0; kk < BK; kk += 32) {
            bf16x8 af[4], bf[4];
            #pragma unroll
            for (int i = 0; i < 4; ++i) {
                int m_l = wm * 64 + i * 16 + r16;
                int sa  = ((kk >> 3) + quad) ^ (m_l & 7);
                af[i] = *reinterpret_cast<const bf16x8*>(&As[p][m_l * BK + sa * 8]);
                int n_l = wn * 64 + i * 16 + r16;
                int sb  = ((kk >> 3) + quad) ^ (n_l & 7);
                bf[i] = *reinterpret_cast<const bf16x8*>(&Bs[p][n_l * BK + sb * 8]);
            }
            #pragma unroll
            for (int i = 0; i < 4; ++i)
                #pragma unroll
                for (int j = 0; j < 4; ++j)
                    acc[i][j] = __builtin_amdgcn_mfma_f32_16x16x32_bf16(
                        af[i], bf[j], acc[i][j], 0, 0, 0);
        }
        p ^= 1;
    }

    // epilogue: bias + SiLU + bf16 store
    // C/D layout: col = lane&15, row = quad*4 + reg   [verified m89]
    #pragma unroll
    for (int j = 0; j < 4; ++j) {
        int col = n0 + wn * 64 + j * 16 + r16;
        float bj = bias[col];
        #pragma unroll
        for (int i = 0; i < 4; ++i) {
            int row_base = m0 + wm * 64 + i * 16 + quad * 4;
            #pragma unroll
            for (int rr = 0; rr < 4; ++rr) {
                float v = acc[i][j][rr] + bj;
                float s = v / (1.f + __expf(-v));
                C[(size_t)(row_base + rr) * H_DIM + col] = __float2bfloat16(s);
            }
        }
    }
}

// ---------------------------------------------------------------------------
// value[m] = sum_n H[m][n] * Wo[n] + bo      (N = 1024 fixed; 1 wave / row)
// ---------------------------------------------------------------------------
__global__ __launch_bounds__(256) void gemv_value_kernel(
    const __hip_bfloat16* __restrict__ H,
    const float* __restrict__ Wo,
    const float* __restrict__ bo_p,
    float* __restrict__ value, int M) {
    int wave = threadIdx.x >> 6, lane = threadIdx.x & 63;
    int row = blockIdx.x * 4 + wave;
    if (row >= M) return;
    const __hip_bfloat16* hrow = H + (size_t)row * H_DIM;
    float sum = 0.f;
    #pragma unroll
    for (int half = 0; half < 2; ++half) {
        int col = half * 512 + lane * 8;
        uint4 raw = *reinterpret_cast<const uint4*>(hrow + col);
        const __hip_bfloat16* hp = reinterpret_cast<const __hip_bfloat16*>(&raw);
        #pragma unroll
        for (int e = 0; e < 8; ++e)
            sum += __bfloat162float(hp[e]) * Wo[col + e];
    }
    #pragma unroll
    for (int off = 32; off > 0; off >>= 1)
        sum += __shfl_down(sum, off, 64);
    if (lane == 0) value[row] = sum + bo_p[0];
}

// ---------------------------------------------------------------------------
// GAE backward scan. value: (T,B) fp32. out: ret (63x512) then baseline.
// ---------------------------------------------------------------------------
__global__ __launch_bounds__(64) void gae_kernel(
    const float* __restrict__ value,
    const float* __restrict__ reward,
    const float* __restrict__ cont,
    float* __restrict__ out) {
    int b = blockIdx.x * blockDim.x + threadIdx.x;
    if (b >= B_DIM) return;
    float adv = 0.f;
    float v_next = value[(T_DIM - 1) * B_DIM + b];
    for (int t = T_DIM - 2; t >= 0; --t) {
        float v_t  = value[t * B_DIM + b];
        float disc = cont[(t + 1) * B_DIM + b] * DISCOUNT;
        float delta = reward[t * B_DIM + b] + disc * v_next - v_t;
        adv = delta + disc * LAM * adv;
        out[t * B_DIM + b] = adv + v_t;                           // ret
        out[(T_DIM - 1) * B_DIM + t * B_DIM + b] = v_t;           // baseline
        v_next = v_t;
    }
}

// ---------------------------------------------------------------------------
extern "C" void kernel_launch(void* const* d_in, const int* in_sizes, int n_in,
                              void* d_out, int out_size, void* d_ws, size_t ws_size,
                              hipStream_t stream) {
    const float* feat   = (const float*)d_in[0];
    const float* reward = (const float*)d_in[1];
    const float* cont   = (const float*)d_in[2];
    const float* W[4]   = {(const float*)d_in[3], (const float*)d_in[5],
                           (const float*)d_in[7], (const float*)d_in[9]};
    const float* bias[4] = {(const float*)d_in[4], (const float*)d_in[6],
                            (const float*)d_in[8], (const float*)d_in[10]};
    const float* Wo = (const float*)d_in[11];
    const float* bo = (const float*)d_in[12];
    float* out = (float*)d_out;

    // workspace layout
    char* ws = (char*)d_ws;
    __hip_bfloat16* Xb = (__hip_bfloat16*)ws; ws += (size_t)M_DIM * D_DIM * 2;   // 96 MB
    __hip_bfloat16* Ha = (__hip_bfloat16*)ws; ws += (size_t)M_DIM * H_DIM * 2;   // 64 MB
    __hip_bfloat16* Hb = (__hip_bfloat16*)ws; ws += (size_t)M_DIM * H_DIM * 2;   // 64 MB
    __hip_bfloat16* Wt0 = (__hip_bfloat16*)ws; ws += (size_t)H_DIM * D_DIM * 2;  // 3 MB
    __hip_bfloat16* Wt1 = (__hip_bfloat16*)ws; ws += (size_t)H_DIM * H_DIM * 2;
    __hip_bfloat16* Wt2 = (__hip_bfloat16*)ws; ws += (size_t)H_DIM * H_DIM * 2;
    __hip_bfloat16* Wt3 = (__hip_bfloat16*)ws; ws += (size_t)H_DIM * H_DIM * 2;
    float* value = (float*)ws; ws += (size_t)M_DIM * 4;

    // 1. feat -> bf16
    long n4 = (long)M_DIM * D_DIM / 4;
    cvt_bf16_kernel<<<(int)((n4 + 255) / 256), 256, 0, stream>>>(feat, Xb, n4);

    // 2. all weight transposes, one launch
    transpose_cvt_all_kernel<<<dim3(D_DIM / 32, H_DIM / 32, 4), dim3(32, 8), 0, stream>>>(
        W[0], W[1], W[2], W[3], Wt0, Wt1, Wt2, Wt3);

    // 3. MLP: 4 GEMM + SiLU layers (1D grid, XCD-swizzled inside)
    const int nblocks = TILES_M * TILES_N;  // 2048
    gemm_silu_kernel<<<nblocks, 256, 0, stream>>>(Xb, Wt0, bias[0], Ha, D_DIM);
    gemm_silu_kernel<<<nblocks, 256, 0, stream>>>(Ha, Wt1, bias[1], Hb, H_DIM);
    gemm_silu_kernel<<<nblocks, 256, 0, stream>>>(Hb, Wt2, bias[2], Ha, H_DIM);
    gemm_silu_kernel<<<nblocks, 256, 0, stream>>>(Ha, Wt3, bias[3], Hb, H_DIM);

    // 4. value head GEMV
    gemv_value_kernel<<<M_DIM / 4, 256, 0, stream>>>(Hb, Wo, bo, value, M_DIM);

    // 5. GAE scan
    gae_kernel<<<8, 64, 0, stream>>>(value, reward, cont, out);
}

// Round 4
// 673.707 us; speedup vs baseline: 1.2673x; 1.1256x over previous
//
#include <hip/hip_runtime.h>
#include <hip/hip_bf16.h>

// Problem constants
#define T_DIM 64
#define B_DIM 512
#define D_DIM 1536
#define H_DIM 1024
#define M_DIM (T_DIM * B_DIM)   // 32768 rows through the MLP
#define DISCOUNT 0.997f
#define LAM 0.95f

// GEMM tiling: 128x256 C-tile, 512 threads (8 waves, 2m x 4n), BK=64.
// Intensity: (A 16KB + B 32KB) staged -> 8.4 MFLOP = 85 FLOP/B (> 65 breakeven
// vs per-CU L2 delivery), vs 64 FLOP/B for the old 128x128 tile.
#define BM 128
#define BN 256
#define BK 64
#define TILES_M 256
#define TILES_N 4
#define N_XCD 8

typedef __bf16 bf16x8 __attribute__((ext_vector_type(8)));
typedef float  f32x4  __attribute__((ext_vector_type(4)));

__device__ __forceinline__ void async_load16(const void* g, void* l) {
    __builtin_amdgcn_global_load_lds(
        (const __attribute__((address_space(1))) void*)g,
        (__attribute__((address_space(3))) void*)l,
        16, 0, 0);
}

__device__ __forceinline__ unsigned short f2bf_raw(float f) {
    __hip_bfloat16 h = __float2bfloat16(f);
    return *reinterpret_cast<unsigned short*>(&h);
}

// ---------------------------------------------------------------------------
// feat fp32 -> bf16, vectorized (float4 in, ushort4 out)
// ---------------------------------------------------------------------------
__global__ __launch_bounds__(256) void cvt_bf16_kernel(
    const float* __restrict__ x, __hip_bfloat16* __restrict__ y, long n4) {
    long i = (long)blockIdx.x * blockDim.x + threadIdx.x;
    if (i >= n4) return;
    float4 v = reinterpret_cast<const float4*>(x)[i];
    ushort4 o;
    o.x = f2bf_raw(v.x);
    o.y = f2bf_raw(v.y);
    o.z = f2bf_raw(v.z);
    o.w = f2bf_raw(v.w);
    reinterpret_cast<ushort4*>(y)[i] = o;
}

// ---------------------------------------------------------------------------
// All 4 weight transposes in one launch. W (K x N fp32) -> Wt (N x K bf16).
// ---------------------------------------------------------------------------
__global__ __launch_bounds__(256) void transpose_cvt_all_kernel(
    const float* __restrict__ W0, const float* __restrict__ W1,
    const float* __restrict__ W2, const float* __restrict__ W3,
    __hip_bfloat16* __restrict__ T0, __hip_bfloat16* __restrict__ T1,
    __hip_bfloat16* __restrict__ T2, __hip_bfloat16* __restrict__ T3) {
    __shared__ float tile[32][33];
    int z = blockIdx.z;
    const float* W;
    __hip_bfloat16* Tt;
    int K;
    if (z == 0)      { W = W0; Tt = T0; K = D_DIM; }
    else if (z == 1) { W = W1; Tt = T1; K = H_DIM; }
    else if (z == 2) { W = W2; Tt = T2; K = H_DIM; }
    else             { W = W3; Tt = T3; K = H_DIM; }
    int k0 = blockIdx.x * 32, n0 = blockIdx.y * 32;
    if (k0 >= K) return;
    int tx = threadIdx.x, ty = threadIdx.y;  // 32 x 8
    #pragma unroll
    for (int r = ty; r < 32; r += 8)
        tile[r][tx] = W[(size_t)(k0 + r) * H_DIM + n0 + tx];
    __syncthreads();
    #pragma unroll
    for (int r = ty; r < 32; r += 8)
        Tt[(size_t)(n0 + r) * K + k0 + tx] = __float2bfloat16(tile[tx][r]);
}

// ---------------------------------------------------------------------------
// C[m][n] = silu( sum_k A[m][k] * Bt[n][k] + bias[n] ), output bf16.
// 128x256 tile, 512 threads, 8 waves (2m x 4n), each wave 64x64 = 4x4 MFMA.
// Single-buffered LDS (48 KB) -> 2-3 blocks/CU; cross-block wave overlap
// covers the barrier drains (r3 showed explicit dbuf pipelining ~neutral;
// intensity, not pipelining, was the binding constraint).
//
// XCD swizzle: hw block l -> xcd = l%8; 4 adjacent local blocks share one
// A panel on the same XCD; Wt N-slices (512 KB x 4) stay L2-resident.
// LDS XOR swizzle via permuted global source column: conflict-free
// (r2 measured SQ_LDS_BANK_CONFLICT = 0 with this scheme).
// ---------------------------------------------------------------------------
__global__ __launch_bounds__(512, 4) void gemm_silu_kernel(
    const __hip_bfloat16* __restrict__ A,
    const __hip_bfloat16* __restrict__ Bt,
    const float* __restrict__ bias,
    __hip_bfloat16* __restrict__ C,
    int K) {

    __shared__ alignas(16) __hip_bfloat16 As[BM * BK];  // 16 KB
    __shared__ alignas(16) __hip_bfloat16 Bs[BN * BK];  // 32 KB

    const int tid  = threadIdx.x;
    const int wave = tid >> 6;         // 0..7
    const int lane = tid & 63;
    const int sub  = lane >> 3;        // staging row within 8-row chunk
    const int quad = lane >> 4;        // 0..3
    const int r16  = lane & 15;        // 0..15
    const int wm   = wave & 1;         // wave row in 2x4
    const int wn   = wave >> 1;        // wave col in 2x4 (0..3)

    // XCD-aware tile assignment: 1024 blocks = 256 M-tiles x 4 N-tiles
    const int l     = blockIdx.x;
    const int xcd   = l & (N_XCD - 1);
    const int local = l >> 3;                  // 0..127
    const int tn    = local & (TILES_N - 1);   // 0..3
    const int tm    = (xcd << 5) | (local >> 2);
    const int m0 = tm * BM;
    const int n0 = tn * BN;

    // swizzled global column for this lane's staging load
    const int scol = (((lane & 7) ^ sub) << 3);

    // staging pointers: A chunks {2w, 2w+1} (16 chunks of 8 rows),
    //                   B chunks {4w..4w+3} (32 chunks of 8 rows)
    const __hip_bfloat16* ga[2];
    const __hip_bfloat16* gb[4];
    #pragma unroll
    for (int i = 0; i < 2; ++i)
        ga[i] = A + (size_t)(m0 + (wave * 2 + i) * 8 + sub) * K + scol;
    #pragma unroll
    for (int i = 0; i < 4; ++i)
        gb[i] = Bt + (size_t)(n0 + (wave * 4 + i) * 8 + sub) * K + scol;

    f32x4 acc[4][4];
    #pragma unroll
    for (int i = 0; i < 4; ++i)
        #pragma unroll
        for (int j = 0; j < 4; ++j)
            acc[i][j] = (f32x4){0.f, 0.f, 0.f, 0.f};

    for (int k0 = 0; k0 < K; k0 += BK) {
        #pragma unroll
        for (int i = 0; i < 2; ++i) {
            async_load16(ga[i], &As[(wave * 2 + i) * 512]);
            ga[i] += BK;
        }
        #pragma unroll
        for (int i = 0; i < 4; ++i) {
            async_load16(gb[i], &Bs[(wave * 4 + i) * 512]);
            gb[i] += BK;
        }
        __syncthreads();

        #pragma unroll
        for (int kk = 0; kk < BK; kk += 32) {
            bf16x8 af[4], bf[4];
            #pragma unroll
            for (int i = 0; i < 4; ++i) {
                int m_l = wm * 64 + i * 16 + r16;
                int sa  = ((kk >> 3) + quad) ^ (m_l & 7);
                af[i] = *reinterpret_cast<const bf16x8*>(&As[m_l * BK + sa * 8]);
                int n_l = wn * 64 + i * 16 + r16;
                int sb  = ((kk >> 3) + quad) ^ (n_l & 7);
                bf[i] = *reinterpret_cast<const bf16x8*>(&Bs[n_l * BK + sb * 8]);
            }
            #pragma unroll
            for (int i = 0; i < 4; ++i)
                #pragma unroll
                for (int j = 0; j < 4; ++j)
                    acc[i][j] = __builtin_amdgcn_mfma_f32_16x16x32_bf16(
                        af[i], bf[j], acc[i][j], 0, 0, 0);
        }
        __syncthreads();
    }

    // epilogue: bias + SiLU + bf16 store
    // C/D layout: col = lane&15, row = quad*4 + reg   [verified m89]
    #pragma unroll
    for (int j = 0; j < 4; ++j) {
        int col = n0 + wn * 64 + j * 16 + r16;
        float bj = bias[col];
        #pragma unroll
        for (int i = 0; i < 4; ++i) {
            int row_base = m0 + wm * 64 + i * 16 + quad * 4;
            #pragma unroll
            for (int rr = 0; rr < 4; ++rr) {
                float v = acc[i][j][rr] + bj;
                float s = v / (1.f + __expf(-v));
                C[(size_t)(row_base + rr) * H_DIM + col] = __float2bfloat16(s);
            }
        }
    }
}

// ---------------------------------------------------------------------------
// value[m] = sum_n H[m][n] * Wo[n] + bo      (N = 1024 fixed; 1 wave / row)
// ---------------------------------------------------------------------------
__global__ __launch_bounds__(256) void gemv_value_kernel(
    const __hip_bfloat16* __restrict__ H,
    const float* __restrict__ Wo,
    const float* __restrict__ bo_p,
    float* __restrict__ value, int M) {
    int wave = threadIdx.x >> 6, lane = threadIdx.x & 63;
    int row = blockIdx.x * 4 + wave;
    if (row >= M) return;
    const __hip_bfloat16* hrow = H + (size_t)row * H_DIM;
    float sum = 0.f;
    #pragma unroll
    for (int half = 0; half < 2; ++half) {
        int col = half * 512 + lane * 8;
        uint4 raw = *reinterpret_cast<const uint4*>(hrow + col);
        const __hip_bfloat16* hp = reinterpret_cast<const __hip_bfloat16*>(&raw);
        #pragma unroll
        for (int e = 0; e < 8; ++e)
            sum += __bfloat162float(hp[e]) * Wo[col + e];
    }
    #pragma unroll
    for (int off = 32; off > 0; off >>= 1)
        sum += __shfl_down(sum, off, 64);
    if (lane == 0) value[row] = sum + bo_p[0];
}

// ---------------------------------------------------------------------------
// GAE backward scan. value: (T,B) fp32. out: ret (63x512) then baseline.
// ---------------------------------------------------------------------------
__global__ __launch_bounds__(64) void gae_kernel(
    const float* __restrict__ value,
    const float* __restrict__ reward,
    const float* __restrict__ cont,
    float* __restrict__ out) {
    int b = blockIdx.x * blockDim.x + threadIdx.x;
    if (b >= B_DIM) return;
    float adv = 0.f;
    float v_next = value[(T_DIM - 1) * B_DIM + b];
    for (int t = T_DIM - 2; t >= 0; --t) {
        float v_t  = value[t * B_DIM + b];
        float disc = cont[(t + 1) * B_DIM + b] * DISCOUNT;
        float delta = reward[t * B_DIM + b] + disc * v_next - v_t;
        adv = delta + disc * LAM * adv;
        out[t * B_DIM + b] = adv + v_t;                           // ret
        out[(T_DIM - 1) * B_DIM + t * B_DIM + b] = v_t;           // baseline
        v_next = v_t;
    }
}

// ---------------------------------------------------------------------------
extern "C" void kernel_launch(void* const* d_in, const int* in_sizes, int n_in,
                              void* d_out, int out_size, void* d_ws, size_t ws_size,
                              hipStream_t stream) {
    const float* feat   = (const float*)d_in[0];
    const float* reward = (const float*)d_in[1];
    const float* cont   = (const float*)d_in[2];
    const float* W[4]   = {(const float*)d_in[3], (const float*)d_in[5],
                           (const float*)d_in[7], (const float*)d_in[9]};
    const float* bias[4] = {(const float*)d_in[4], (const float*)d_in[6],
                            (const float*)d_in[8], (const float*)d_in[10]};
    const float* Wo = (const float*)d_in[11];
    const float* bo = (const float*)d_in[12];
    float* out = (float*)d_out;

    // workspace layout
    char* ws = (char*)d_ws;
    __hip_bfloat16* Xb = (__hip_bfloat16*)ws; ws += (size_t)M_DIM * D_DIM * 2;   // 96 MB
    __hip_bfloat16* Ha = (__hip_bfloat16*)ws; ws += (size_t)M_DIM * H_DIM * 2;   // 64 MB
    __hip_bfloat16* Hb = (__hip_bfloat16*)ws; ws += (size_t)M_DIM * H_DIM * 2;   // 64 MB
    __hip_bfloat16* Wt0 = (__hip_bfloat16*)ws; ws += (size_t)H_DIM * D_DIM * 2;  // 3 MB
    __hip_bfloat16* Wt1 = (__hip_bfloat16*)ws; ws += (size_t)H_DIM * H_DIM * 2;
    __hip_bfloat16* Wt2 = (__hip_bfloat16*)ws; ws += (size_t)H_DIM * H_DIM * 2;
    __hip_bfloat16* Wt3 = (__hip_bfloat16*)ws; ws += (size_t)H_DIM * H_DIM * 2;
    float* value = (float*)ws; ws += (size_t)M_DIM * 4;

    // 1. feat -> bf16
    long n4 = (long)M_DIM * D_DIM / 4;
    cvt_bf16_kernel<<<(int)((n4 + 255) / 256), 256, 0, stream>>>(feat, Xb, n4);

    // 2. all weight transposes, one launch
    transpose_cvt_all_kernel<<<dim3(D_DIM / 32, H_DIM / 32, 4), dim3(32, 8), 0, stream>>>(
        W[0], W[1], W[2], W[3], Wt0, Wt1, Wt2, Wt3);

    // 3. MLP: 4 GEMM + SiLU layers (1D grid, XCD-swizzled inside)
    const int nblocks = TILES_M * TILES_N;  // 1024
    gemm_silu_kernel<<<nblocks, 512, 0, stream>>>(Xb, Wt0, bias[0], Ha, D_DIM);
    gemm_silu_kernel<<<nblocks, 512, 0, stream>>>(Ha, Wt1, bias[1], Hb, H_DIM);
    gemm_silu_kernel<<<nblocks, 512, 0, stream>>>(Hb, Wt2, bias[2], Ha, H_DIM);
    gemm_silu_kernel<<<nblocks, 512, 0, stream>>>(Ha, Wt3, bias[3], Hb, H_DIM);

    // 4. value head GEMV
    gemv_value_kernel<<<M_DIM / 4, 256, 0, stream>>>(Hb, Wo, bo, value, M_DIM);

    // 5. GAE scan
    gae_kernel<<<8, 64, 0, stream>>>(value, reward, cont, out);
}